// Round 20
// baseline (74.026 us; speedup 1.0000x reference)
//
#include <hip/hip_runtime.h>
#include <stdint.h>

#define B_ 128
#define Q_ 2048
#define C_ 8
#define L_ 256
#define K_ 64
#define S_ 1985            // Q - K + 1
#define KC_ 512            // K*C

typedef short s16x8 __attribute__((ext_vector_type(8)));
typedef float f32x16 __attribute__((ext_vector_type(16)));

__device__ __forceinline__ unsigned short f2bf(float f) {
    unsigned u = __float_as_uint(f);
    u += 0x7FFFu + ((u >> 16) & 1u);        // round-to-nearest-even
    return (unsigned short)(u >> 16);
}
// monotone float -> unsigned encoding (order-preserving), for atomicMin
__device__ __forceinline__ unsigned fenc(float f) {
    unsigned u = __float_as_uint(f);
    return (u & 0x80000000u) ? ~u : (u | 0x80000000u);
}
__device__ __forceinline__ float fdec(unsigned k) {
    unsigned u = (k & 0x80000000u) ? (k ^ 0x80000000u) : ~k;
    return __uint_as_float(u);
}
__device__ __forceinline__ void async_copy16(void* lds_dst, const void* g_src) {
    __builtin_amdgcn_global_load_lds(
        (const __attribute__((address_space(1))) void*)g_src,
        (__attribute__((address_space(3))) void*)lds_dst, 16, 0, 0);
}

// ---- fused prep: ts cast+window-norms | shapelet k-major+norms | init ----
__global__ __launch_bounds__(256) void k_prep(const float* __restrict__ ts,
                                              const float* __restrict__ sh,
                                              uint4* __restrict__ tsb,
                                              uint4* __restrict__ shb2,
                                              float* __restrict__ shsq,
                                              unsigned* __restrict__ extg,
                                              unsigned* __restrict__ hmin) {
    __shared__ float t2[2048];
    const int bid = blockIdx.x, t = threadIdx.x;
    if (bid < 128) {
        const int b = bid;
        #pragma unroll
        for (int j = 0; j < 8; ++j) {
            int r = j * 256 + t;
            const float4* p = (const float4*)(ts + ((size_t)b * Q_ + r) * C_);
            float4 x = p[0], y = p[1];
            union { unsigned short h[8]; uint4 v; } u;
            u.h[0] = f2bf(x.x); u.h[1] = f2bf(x.y); u.h[2] = f2bf(x.z); u.h[3] = f2bf(x.w);
            u.h[4] = f2bf(y.x); u.h[5] = f2bf(y.y); u.h[6] = f2bf(y.z); u.h[7] = f2bf(y.w);
            tsb[(size_t)b * Q_ + r] = u.v;
            t2[r] = x.x*x.x + x.y*x.y + x.z*x.z + x.w*x.w
                  + y.x*y.x + y.y*y.y + y.z*y.z + y.w*y.w;
        }
        __syncthreads();
        int s0 = t * 8;
        float w = 0.f;
        if (s0 < S_) {
            #pragma unroll 16
            for (int k = 0; k < K_; ++k) w += t2[s0 + k];
        }
        #pragma unroll
        for (int j = 0; j < 8; ++j) {
            int s = s0 + j;
            unsigned word = 0x0000FF80u;              // slot0 = -inf, slot1 = 0
            if (s < S_) {
                float v = -0.5f * w;
                unsigned short hh = f2bf(v);
                float hf = __uint_as_float((unsigned)hh << 16);
                unsigned short ll = f2bf(v - hf);
                word = (unsigned)hh | ((unsigned)ll << 16);
            }
            extg[(size_t)b * Q_ + s] = word;
            if (s + K_ < Q_) w += t2[s + K_] - t2[s]; // slide window
        }
    } else if (bid < 192) {
        const int l = (bid - 128) * 4 + (t >> 6);     // shapelet index
        const int c = t & 63;                         // 16B-chunk index (0..63)
        const float4* p = (const float4*)(sh + (size_t)l * KC_) + c * 2;
        float4 x = p[0], y = p[1];
        union { unsigned short h[8]; uint4 v; } u;
        u.h[0] = f2bf(x.x); u.h[1] = f2bf(x.y); u.h[2] = f2bf(x.z); u.h[3] = f2bf(x.w);
        u.h[4] = f2bf(y.x); u.h[5] = f2bf(y.y); u.h[6] = f2bf(y.z); u.h[7] = f2bf(y.w);
        shb2[c * L_ + l] = u.v;                       // k-major [chunk][col]
        float ss = x.x*x.x + x.y*x.y + x.z*x.z + x.w*x.w
                 + y.x*y.x + y.y*y.y + y.z*y.z + y.w*y.w;
        #pragma unroll
        for (int off = 32; off >= 1; off >>= 1) ss += __shfl_down(ss, off, 64);
        if (c == 0) shsq[l] = ss;
    } else if (bid < 194) {
        uint4 z; z.x = z.y = z.z = z.w = 0u;
        tsb[B_ * Q_ + (bid - 192) * 256 + t] = z;
    } else {
        hmin[(bid - 194) * 256 + t] = 0xFFFFFFFFu;
    }
}

// ---- main: implicit-GEMM conv + min-pool; wave tile 128x128, 1 wave/SIMD ----
// 256-thr blocks (4 waves as 2m x 2n), wave tile 128x128, acc 4x4 = 256
// AGPR (+~90 VGPR = ~350 < 512 -> 1 wave/SIMD, true fit). Per kk: 8
// ds_read_b128 (96 LDS-cyc) feed 16 INDEPENDENT MFMAs (128 pipe-cyc):
// 0.5 KB/MFMA -> LDS 49k cyc/CU < MFMA 65.5k -> MFMA-bound by
// construction; single-wave ILP covers the ~120-cyc read latency.
// Block tile 256x256 (all shapelet cols). B in k-major [ch][col] 16B
// frags, K64-chunk double-buffered (2 x 32 KB, contiguous ->
// conflict-free, no swizzle); A full-K (320 rows, 5 KB) staged once.
// Grid (8 m, 128 b) = 1024 blocks, 4 sequential per CU. wq + validity
// via K-extension MFMA (ext rows reach exactly 2047; extg>=S_ = -inf).
__global__ __launch_bounds__(256, 1) void k_main(
    const uint4* __restrict__ tsb,        // bf16 [B][Q][C] (+512 pad rows)
    const uint4* __restrict__ shb2,       // bf16 k-major [64][256] 16B frags
    const unsigned* __restrict__ extg,    // [B][2048] packed (-wq/2) pairs
    const float* __restrict__ shsq,       // [L]
    unsigned*    __restrict__ hmin)       // [B][L] encoded min
{
    __shared__ uint4 b_lds[2][2048];      // [buf][ch(8) x col(256)] = 2x32 KB
    __shared__ uint4 a_lds[320];          // 320 ts-rows x 16B = 5 KB

    const int mt   = blockIdx.x;          // 0..7
    const int b    = blockIdx.y;
    const int r0   = mt * 256;
    const int tid  = threadIdx.x;
    const int lane = tid & 63;
    const int wv   = tid >> 6;            // 0..3
    const int l31  = lane & 31;
    const int hi   = lane >> 5;
    const int wm   = wv >> 1;             // 0..1 row group of 128
    const int wn   = wv & 1;              // 0..1 col group of 128

    // stage B K64-chunk p into buf: 32 KB = 8 insts x 256 thr
    #define STAGE_B(p, buf)                                                    \
        {                                                                      \
            _Pragma("unroll")                                                  \
            for (int i = 0; i < 8; ++i) {                                      \
                int e = i * 256 + tid;    /* 0..2047 */                        \
                async_copy16((char*)&b_lds[buf][e],                            \
                             (const char*)(shb2 + ((p) * 8 + (e >> 8)) * L_   \
                                           + (e & 255)));                      \
            }                                                                  \
        }

    // stage A once: 320 rows x 16B (rows r0..r0+319; tsb has 512 pad rows)
    {
        const char* gA = (const char*)(tsb + (size_t)b * Q_ + r0);
        async_copy16((char*)a_lds + tid * 16, gA + tid * 16);
        if (tid < 64)
            async_copy16((char*)a_lds + (256 + tid) * 16, gA + (256 + tid) * 16);
    }
    STAGE_B(0, 0)
    __syncthreads();   // A + B0 landed

    const f32x16 fz = {0.f,0.f,0.f,0.f,0.f,0.f,0.f,0.f,
                       0.f,0.f,0.f,0.f,0.f,0.f,0.f,0.f};
    f32x16 acc00 = fz, acc01 = fz, acc02 = fz, acc03 = fz;
    f32x16 acc10 = fz, acc11 = fz, acc12 = fz, acc13 = fz;
    f32x16 acc20 = fz, acc21 = fz, acc22 = fz, acc23 = fz;
    f32x16 acc30 = fz, acc31 = fz, acc32 = fz, acc33 = fz;

    const char* ab    = (const char*)a_lds;
    const int   arow  = wm * 128 + l31 + hi;         // ts-row base in tile
    const int   bcolb = (wn * 128 + l31) * 16;       // byte offset of col

    // one kk step: 4 A-frags + 4 B-frags -> 16 MFMAs (j = kk within chunk)
    #define KKSTEP(p, j, bb)                                                   \
        {                                                                      \
            int ar = (arow + 2 * ((p) * 4 + (j))) * 16;                        \
            s16x8 a0 = *(const s16x8*)(ab + ar);                               \
            s16x8 a1 = *(const s16x8*)(ab + ar + 512);    /* +32 rows */       \
            s16x8 a2 = *(const s16x8*)(ab + ar + 1024);   /* +64 rows */       \
            s16x8 a3 = *(const s16x8*)(ab + ar + 1536);   /* +96 rows */       \
            const char* bp = (bb) + (2 * (j) + hi) * 4096 + bcolb;             \
            s16x8 b0 = *(const s16x8*)(bp);                                    \
            s16x8 b1 = *(const s16x8*)(bp + 512);         /* +32 cols */       \
            s16x8 b2 = *(const s16x8*)(bp + 1024);        /* +64 cols */       \
            s16x8 b3 = *(const s16x8*)(bp + 1536);        /* +96 cols */       \
            __builtin_amdgcn_s_setprio(1);                                     \
            acc00 = __builtin_amdgcn_mfma_f32_32x32x16_bf16(a0, b0, acc00, 0, 0, 0); \
            acc01 = __builtin_amdgcn_mfma_f32_32x32x16_bf16(a0, b1, acc01, 0, 0, 0); \
            acc02 = __builtin_amdgcn_mfma_f32_32x32x16_bf16(a0, b2, acc02, 0, 0, 0); \
            acc03 = __builtin_amdgcn_mfma_f32_32x32x16_bf16(a0, b3, acc03, 0, 0, 0); \
            acc10 = __builtin_amdgcn_mfma_f32_32x32x16_bf16(a1, b0, acc10, 0, 0, 0); \
            acc11 = __builtin_amdgcn_mfma_f32_32x32x16_bf16(a1, b1, acc11, 0, 0, 0); \
            acc12 = __builtin_amdgcn_mfma_f32_32x32x16_bf16(a1, b2, acc12, 0, 0, 0); \
            acc13 = __builtin_amdgcn_mfma_f32_32x32x16_bf16(a1, b3, acc13, 0, 0, 0); \
            acc20 = __builtin_amdgcn_mfma_f32_32x32x16_bf16(a2, b0, acc20, 0, 0, 0); \
            acc21 = __builtin_amdgcn_mfma_f32_32x32x16_bf16(a2, b1, acc21, 0, 0, 0); \
            acc22 = __builtin_amdgcn_mfma_f32_32x32x16_bf16(a2, b2, acc22, 0, 0, 0); \
            acc23 = __builtin_amdgcn_mfma_f32_32x32x16_bf16(a2, b3, acc23, 0, 0, 0); \
            acc30 = __builtin_amdgcn_mfma_f32_32x32x16_bf16(a3, b0, acc30, 0, 0, 0); \
            acc31 = __builtin_amdgcn_mfma_f32_32x32x16_bf16(a3, b1, acc31, 0, 0, 0); \
            acc32 = __builtin_amdgcn_mfma_f32_32x32x16_bf16(a3, b2, acc32, 0, 0, 0); \
            acc33 = __builtin_amdgcn_mfma_f32_32x32x16_bf16(a3, b3, acc33, 0, 0, 0); \
            __builtin_amdgcn_s_setprio(0);                                     \
        }

    #pragma unroll 1
    for (int p = 0; p < 8; ++p) {
        if (p < 7) STAGE_B(p + 1, (p + 1) & 1)       // prefetch next chunk
        const char* bb = (const char*)&b_lds[p & 1][0];
        KKSTEP(p, 0, bb)
        KKSTEP(p, 1, bb)
        KKSTEP(p, 2, bb)
        KKSTEP(p, 3, bb)
        __syncthreads();   // reads of buf(p) done; stage(p+1) landed
    }

    // K-extension: fold wq (+ -inf invalid mask) into all 16 accs.
    // ext rows: r0 + wm*128 + {0,32,64,96} + l31, max = 2047 (in range).
    union UU { unsigned u[4]; s16x8 v; };
    UU be; be.u[0] = hi ? 0u : 0x3F803F80u;          // k-slots 0,1 = 1.0
    be.u[1] = 0u; be.u[2] = 0u; be.u[3] = 0u;
    {
        size_t eb = (size_t)b * Q_ + r0 + wm * 128 + l31;
        unsigned w0 = extg[eb];
        unsigned w1 = extg[eb + 32];
        unsigned w2 = extg[eb + 64];
        unsigned w3 = extg[eb + 96];
        UU a0, a1, a2, a3;
        a0.u[0] = hi ? 0u : w0; a0.u[1] = 0; a0.u[2] = 0; a0.u[3] = 0;
        a1.u[0] = hi ? 0u : w1; a1.u[1] = 0; a1.u[2] = 0; a1.u[3] = 0;
        a2.u[0] = hi ? 0u : w2; a2.u[1] = 0; a2.u[2] = 0; a2.u[3] = 0;
        a3.u[0] = hi ? 0u : w3; a3.u[1] = 0; a3.u[2] = 0; a3.u[3] = 0;
        acc00 = __builtin_amdgcn_mfma_f32_32x32x16_bf16(a0.v, be.v, acc00, 0, 0, 0);
        acc01 = __builtin_amdgcn_mfma_f32_32x32x16_bf16(a0.v, be.v, acc01, 0, 0, 0);
        acc02 = __builtin_amdgcn_mfma_f32_32x32x16_bf16(a0.v, be.v, acc02, 0, 0, 0);
        acc03 = __builtin_amdgcn_mfma_f32_32x32x16_bf16(a0.v, be.v, acc03, 0, 0, 0);
        acc10 = __builtin_amdgcn_mfma_f32_32x32x16_bf16(a1.v, be.v, acc10, 0, 0, 0);
        acc11 = __builtin_amdgcn_mfma_f32_32x32x16_bf16(a1.v, be.v, acc11, 0, 0, 0);
        acc12 = __builtin_amdgcn_mfma_f32_32x32x16_bf16(a1.v, be.v, acc12, 0, 0, 0);
        acc13 = __builtin_amdgcn_mfma_f32_32x32x16_bf16(a1.v, be.v, acc13, 0, 0, 0);
        acc20 = __builtin_amdgcn_mfma_f32_32x32x16_bf16(a2.v, be.v, acc20, 0, 0, 0);
        acc21 = __builtin_amdgcn_mfma_f32_32x32x16_bf16(a2.v, be.v, acc21, 0, 0, 0);
        acc22 = __builtin_amdgcn_mfma_f32_32x32x16_bf16(a2.v, be.v, acc22, 0, 0, 0);
        acc23 = __builtin_amdgcn_mfma_f32_32x32x16_bf16(a2.v, be.v, acc23, 0, 0, 0);
        acc30 = __builtin_amdgcn_mfma_f32_32x32x16_bf16(a3.v, be.v, acc30, 0, 0, 0);
        acc31 = __builtin_amdgcn_mfma_f32_32x32x16_bf16(a3.v, be.v, acc31, 0, 0, 0);
        acc32 = __builtin_amdgcn_mfma_f32_32x32x16_bf16(a3.v, be.v, acc32, 0, 0, 0);
        acc33 = __builtin_amdgcn_mfma_f32_32x32x16_bf16(a3.v, be.v, acc33, 0, 0, 0);
    }

    // register-only fold: -2*acc already includes wq and the mask
    const float inf = __builtin_inff();
    float rm0 = inf, rm1 = inf, rm2 = inf, rm3 = inf;
    #pragma unroll
    for (int r = 0; r < 16; ++r) {
        rm0 = fminf(rm0, fminf(fminf(-2.f * acc00[r], -2.f * acc10[r]),
                               fminf(-2.f * acc20[r], -2.f * acc30[r])));
        rm1 = fminf(rm1, fminf(fminf(-2.f * acc01[r], -2.f * acc11[r]),
                               fminf(-2.f * acc21[r], -2.f * acc31[r])));
        rm2 = fminf(rm2, fminf(fminf(-2.f * acc02[r], -2.f * acc12[r]),
                               fminf(-2.f * acc22[r], -2.f * acc32[r])));
        rm3 = fminf(rm3, fminf(fminf(-2.f * acc03[r], -2.f * acc13[r]),
                               fminf(-2.f * acc23[r], -2.f * acc33[r])));
    }

    // epilogue: + shsq (commutes with min), scale, reduce halves, atomic
    const int colg = wn * 128 + l31;
    rm0 = (rm0 + shsq[colg])      * (1.f / 512.f);
    rm1 = (rm1 + shsq[colg + 32]) * (1.f / 512.f);
    rm2 = (rm2 + shsq[colg + 64]) * (1.f / 512.f);
    rm3 = (rm3 + shsq[colg + 96]) * (1.f / 512.f);
    rm0 = fminf(rm0, __shfl_xor(rm0, 32, 64));
    rm1 = fminf(rm1, __shfl_xor(rm1, 32, 64));
    rm2 = fminf(rm2, __shfl_xor(rm2, 32, 64));
    rm3 = fminf(rm3, __shfl_xor(rm3, 32, 64));
    if (hi == 0) {
        atomicMin(&hmin[b * L_ + colg],      fenc(rm0));
        atomicMin(&hmin[b * L_ + colg + 32], fenc(rm1));
        atomicMin(&hmin[b * L_ + colg + 64], fenc(rm2));
        atomicMin(&hmin[b * L_ + colg + 96], fenc(rm3));
    }
}

// ---- final: gating + FC [B,L] -> [B,2] ----
__global__ __launch_bounds__(256) void k_final(const unsigned* __restrict__ hmin,
                                               const float* __restrict__ gating,
                                               const float* __restrict__ w,
                                               const float* __restrict__ bias,
                                               float* __restrict__ out) {
    const int b = blockIdx.x, t = threadIdx.x;       // 256 threads = L
    float v = fdec(hmin[b * L_ + t]);
    float g = 1.f / (1.f + __expf(-gating[t]));
    float mg = v * g;
    float p0 = mg * w[t];
    float p1 = mg * w[L_ + t];
    #pragma unroll
    for (int off = 32; off >= 1; off >>= 1) {
        p0 += __shfl_down(p0, off, 64);
        p1 += __shfl_down(p1, off, 64);
    }
    __shared__ float r0[4], r1[4];
    int wvi = t >> 6, ln = t & 63;
    if (ln == 0) { r0[wvi] = p0; r1[wvi] = p1; }
    __syncthreads();
    if (t == 0) {
        out[b * 2 + 0] = r0[0] + r0[1] + r0[2] + r0[3] + bias[0];
        out[b * 2 + 1] = r1[0] + r1[1] + r1[2] + r1[3] + bias[1];
    }
}

extern "C" void kernel_launch(void* const* d_in, const int* in_sizes, int n_in,
                              void* d_out, int out_size, void* d_ws, size_t ws_size,
                              hipStream_t stream) {
    const float* ts     = (const float*)d_in[0];
    const float* sh     = (const float*)d_in[1];
    const float* gating = (const float*)d_in[2];
    const float* fw     = (const float*)d_in[3];
    const float* fb     = (const float*)d_in[4];
    float* out = (float*)d_out;

    char* ws = (char*)d_ws;
    uint4*    tsb  = (uint4*)ws;                         // 4 MiB + 8 KB pad
    uint4*    shb2 = (uint4*)(ws + 4202496);             // 256 KiB (k-major)
    float*    shsq = (float*)(ws + 4464640);             // 1 KiB
    unsigned* hmin = (unsigned*)(ws + 4465664);          // 128 KiB
    unsigned* extg = (unsigned*)(ws + 4596736);          // 1 MiB

    k_prep<<<322, 256, 0, stream>>>(ts, sh, tsb, shb2, shsq, extg, hmin);
    dim3 grid(8, B_);
    k_main<<<grid, 256, 0, stream>>>(tsb, shb2, extg, shsq, hmin);
    k_final<<<128, 256, 0, stream>>>(hmin, gating, fw, fb, out);
}

// Round 21
// 62.377 us; speedup vs baseline: 1.1868x; 1.1868x over previous
//
#include <hip/hip_runtime.h>
#include <stdint.h>

#define B_ 128
#define Q_ 2048
#define C_ 8
#define L_ 256
#define K_ 64
#define S_ 1985            // Q - K + 1
#define KC_ 512            // K*C
#define BNC_ 64            // shapelet cols per block tile
#define NNT_ 4             // 256 / 64 n-tiles

typedef short s16x8 __attribute__((ext_vector_type(8)));
typedef float f32x16 __attribute__((ext_vector_type(16)));

__device__ __forceinline__ unsigned short f2bf(float f) {
    unsigned u = __float_as_uint(f);
    u += 0x7FFFu + ((u >> 16) & 1u);        // round-to-nearest-even
    return (unsigned short)(u >> 16);
}
// monotone float -> unsigned encoding (order-preserving), for atomicMin
__device__ __forceinline__ unsigned fenc(float f) {
    unsigned u = __float_as_uint(f);
    return (u & 0x80000000u) ? ~u : (u | 0x80000000u);
}
__device__ __forceinline__ float fdec(unsigned k) {
    unsigned u = (k & 0x80000000u) ? (k ^ 0x80000000u) : ~k;
    return __uint_as_float(u);
}
__device__ __forceinline__ void async_copy16(void* lds_dst, const void* g_src) {
    __builtin_amdgcn_global_load_lds(
        (const __attribute__((address_space(1))) void*)g_src,
        (__attribute__((address_space(3))) void*)lds_dst, 16, 0, 0);
}

// ---- fused prep (single launch): ts cast + window-norm ext pairs |
//      shapelet col-blobs + norms | tsb pad | hmin init ----
__global__ __launch_bounds__(256) void k_prep(const float* __restrict__ ts,
                                              const float* __restrict__ sh,
                                              uint4* __restrict__ tsb,
                                              uint4* __restrict__ shb,
                                              float* __restrict__ shsq,
                                              unsigned* __restrict__ extg,
                                              unsigned* __restrict__ hmin) {
    __shared__ float t2[2048];
    const int bid = blockIdx.x, t = threadIdx.x;
    if (bid < 128) {
        const int b = bid;
        #pragma unroll
        for (int j = 0; j < 8; ++j) {
            int r = j * 256 + t;
            const float4* p = (const float4*)(ts + ((size_t)b * Q_ + r) * C_);
            float4 x = p[0], y = p[1];
            union { unsigned short h[8]; uint4 v; } u;
            u.h[0] = f2bf(x.x); u.h[1] = f2bf(x.y); u.h[2] = f2bf(x.z); u.h[3] = f2bf(x.w);
            u.h[4] = f2bf(y.x); u.h[5] = f2bf(y.y); u.h[6] = f2bf(y.z); u.h[7] = f2bf(y.w);
            tsb[(size_t)b * Q_ + r] = u.v;
            t2[r] = x.x*x.x + x.y*x.y + x.z*x.z + x.w*x.w
                  + y.x*y.x + y.y*y.y + y.z*y.z + y.w*y.w;
        }
        __syncthreads();
        int s0 = t * 8;
        float w = 0.f;
        if (s0 < S_) {
            #pragma unroll 16
            for (int k = 0; k < K_; ++k) w += t2[s0 + k];
        }
        #pragma unroll
        for (int j = 0; j < 8; ++j) {
            int s = s0 + j;
            unsigned word = 0x0000FF80u;              // slot0 = -inf, slot1 = 0
            if (s < S_) {
                float v = -0.5f * w;
                unsigned short hh = f2bf(v);
                float hf = __uint_as_float((unsigned)hh << 16);
                unsigned short ll = f2bf(v - hf);
                word = (unsigned)hh | ((unsigned)ll << 16);
            }
            extg[(size_t)b * Q_ + s] = word;
            if (s + K_ < Q_) w += t2[s + K_] - t2[s]; // slide window
        }
    } else if (bid < 192) {
        const int l = (bid - 128) * 4 + (t >> 6);     // shapelet index
        const int c = t & 63;                         // k16-chunk index
        const float4* p = (const float4*)(sh + (size_t)l * KC_) + c * 2;
        float4 x = p[0], y = p[1];
        union { unsigned short h[8]; uint4 v; } u;
        u.h[0] = f2bf(x.x); u.h[1] = f2bf(x.y); u.h[2] = f2bf(x.z); u.h[3] = f2bf(x.w);
        u.h[4] = f2bf(y.x); u.h[5] = f2bf(y.y); u.h[6] = f2bf(y.z); u.h[7] = f2bf(y.w);
        shb[l * 64 + c] = u.v;                        // col blob [l][chunk]
        float ss = x.x*x.x + x.y*x.y + x.z*x.z + x.w*x.w
                 + y.x*y.x + y.y*y.y + y.z*y.z + y.w*y.w;
        #pragma unroll
        for (int off = 32; off >= 1; off >>= 1) ss += __shfl_down(ss, off, 64);
        if (c == 0) shsq[l] = ss;
    } else if (bid < 194) {
        uint4 z; z.x = z.y = z.z = z.w = 0u;
        tsb[B_ * Q_ + (bid - 192) * 256 + t] = z;
    } else {
        hmin[(bid - 194) * 256 + t] = 0xFFFFFFFFu;
    }
}

// ---- main (R9 structure — best measured k_main, 52.1 µs): acc 4x2,
// long-lived blocks, B 64-col full-K staged once, wq-in-GEMM ----
// grid 4 n-tiles x 128 b = 512 blocks (2/CU). Block stages B (64 KB)
// ONCE, then 4 m-iters of 512 windows. Wave tile 128x64 (acc 4x2):
// 6 ds_read_b128 per 8 MFMAs (0.75 KB/MFMA — family optimum). wq folds
// in via a K-extension MFMA step (A = -wq/2 bf16 pair from e_lds;
// B = constant 1s); invalid windows carry -inf -> masked for free.
__global__ __launch_bounds__(256, 2) void k_main(
    const uint4* __restrict__ tsb,        // bf16 [B][Q][C] (+512 pad rows)
    const char*  __restrict__ shb,        // bf16 [L][512] bytes (col blobs)
    const unsigned* __restrict__ extg,    // [B][2048] packed (-wq/2) pairs
    const float* __restrict__ shsq,       // [L]
    unsigned*    __restrict__ hmin)       // [B][L] encoded min
{
    __shared__ uint4 b_lds4[4096];        // 64 cols x 64 chunks x 16B = 64 KB
    __shared__ uint4 a_lds4[576];         // 576 ts-rows x 16B = 9 KB
    __shared__ uint4 e_lds4[128];         // 512 ext words = 2 KB

    const int nt   = blockIdx.x;          // 0..3
    const int b    = blockIdx.y;
    const int c0   = nt * BNC_;
    const int tid  = threadIdx.x;
    const int lane = tid & 63;
    const int wv   = tid >> 6;            // 0..3 = row group of 128
    const int l31  = lane & 31;
    const int hi   = lane >> 5;

    // stage A (576 rows) + ext (512 words) for m-tile mi_ (linear, async)
    #define STAGE_AE(mi_)                                                      \
        {                                                                      \
            const char* gA = (const char*)(tsb + (size_t)b * Q_ + (mi_) * 512);\
            for (int rr = tid; rr < 576; rr += 256)                            \
                async_copy16((char*)a_lds4 + rr * 16, gA + rr * 16);           \
            if (tid < 128)                                                     \
                async_copy16((char*)e_lds4 + tid * 16,                         \
                             (const char*)(extg + (size_t)b * Q_ + (mi_) * 512)\
                             + tid * 16);                                      \
        }

    // stage B once: 64 cols x 1 KB; swizzle chunk' = chunk ^ (col&31)
    #pragma unroll
    for (int it = 0; it < 16; ++it) {
        int col  = wv * 16 + it;
        const char* g = shb + ((size_t)(c0 + col)) * 1024
                      + ((lane ^ (col & 31)) << 4);
        async_copy16((char*)b_lds4 + col * 1024, g);
    }
    STAGE_AE(0)
    __syncthreads();   // B + A0 + ext0 landed

    const f32x16 fz = {0.f,0.f,0.f,0.f,0.f,0.f,0.f,0.f,
                       0.f,0.f,0.f,0.f,0.f,0.f,0.f,0.f};
    const float inf = __builtin_inff();
    float rm0 = inf, rm1 = inf;           // running min across m-iters

    const char* bb    = (const char*)b_lds4;
    const char* ab    = (const char*)a_lds4;
    const char* eb    = (const char*)e_lds4;
    const int   abase = (wv * 128 + l31 + hi) * 16;  // ts-row byte base
    const int   bcol  = l31 * 1024;                  // B col byte base

    union UU { unsigned u[4]; s16x8 v; };
    UU be; be.u[0] = hi ? 0u : 0x3F803F80u;          // k-slots 0,1 = 1.0
    be.u[1] = 0u; be.u[2] = 0u; be.u[3] = 0u;

    #pragma unroll 1
    for (int mi = 0; mi < 4; ++mi) {
        f32x16 acc00 = fz, acc01 = fz;    // row-group 0 (+0),   cols l31/l31+32
        f32x16 acc10 = fz, acc11 = fz;    // row-group 1 (+32)
        f32x16 acc20 = fz, acc21 = fz;    // row-group 2 (+64)
        f32x16 acc30 = fz, acc31 = fz;    // row-group 3 (+96)

        #pragma unroll
        for (int kk = 0; kk < 32; ++kk) {
            s16x8 a0 = *(const s16x8*)(ab + abase + kk * 32);
            s16x8 a1 = *(const s16x8*)(ab + abase + kk * 32 + 512);
            s16x8 a2 = *(const s16x8*)(ab + abase + kk * 32 + 1024);
            s16x8 a3 = *(const s16x8*)(ab + abase + kk * 32 + 1536);
            int ch = (((kk << 1) + hi) ^ l31) << 4;
            s16x8 b0 = *(const s16x8*)(bb + bcol + ch);
            s16x8 b1 = *(const s16x8*)(bb + bcol + ch + 32768);  // +32 cols
            __builtin_amdgcn_s_setprio(1);
            acc00 = __builtin_amdgcn_mfma_f32_32x32x16_bf16(a0, b0, acc00, 0, 0, 0);
            acc01 = __builtin_amdgcn_mfma_f32_32x32x16_bf16(a0, b1, acc01, 0, 0, 0);
            acc10 = __builtin_amdgcn_mfma_f32_32x32x16_bf16(a1, b0, acc10, 0, 0, 0);
            acc11 = __builtin_amdgcn_mfma_f32_32x32x16_bf16(a1, b1, acc11, 0, 0, 0);
            acc20 = __builtin_amdgcn_mfma_f32_32x32x16_bf16(a2, b0, acc20, 0, 0, 0);
            acc21 = __builtin_amdgcn_mfma_f32_32x32x16_bf16(a2, b1, acc21, 0, 0, 0);
            acc30 = __builtin_amdgcn_mfma_f32_32x32x16_bf16(a3, b0, acc30, 0, 0, 0);
            acc31 = __builtin_amdgcn_mfma_f32_32x32x16_bf16(a3, b1, acc31, 0, 0, 0);
            __builtin_amdgcn_s_setprio(0);
        }
        // K-extension step: fold wq (and invalid-window -inf) into acc
        {
            unsigned w0 = *(const unsigned*)(eb + (wv * 128 +  0 + l31) * 4);
            unsigned w1 = *(const unsigned*)(eb + (wv * 128 + 32 + l31) * 4);
            unsigned w2 = *(const unsigned*)(eb + (wv * 128 + 64 + l31) * 4);
            unsigned w3 = *(const unsigned*)(eb + (wv * 128 + 96 + l31) * 4);
            UU ae0, ae1, ae2, ae3;
            ae0.u[0] = hi ? 0u : w0; ae0.u[1] = 0; ae0.u[2] = 0; ae0.u[3] = 0;
            ae1.u[0] = hi ? 0u : w1; ae1.u[1] = 0; ae1.u[2] = 0; ae1.u[3] = 0;
            ae2.u[0] = hi ? 0u : w2; ae2.u[1] = 0; ae2.u[2] = 0; ae2.u[3] = 0;
            ae3.u[0] = hi ? 0u : w3; ae3.u[1] = 0; ae3.u[2] = 0; ae3.u[3] = 0;
            acc00 = __builtin_amdgcn_mfma_f32_32x32x16_bf16(ae0.v, be.v, acc00, 0, 0, 0);
            acc01 = __builtin_amdgcn_mfma_f32_32x32x16_bf16(ae0.v, be.v, acc01, 0, 0, 0);
            acc10 = __builtin_amdgcn_mfma_f32_32x32x16_bf16(ae1.v, be.v, acc10, 0, 0, 0);
            acc11 = __builtin_amdgcn_mfma_f32_32x32x16_bf16(ae1.v, be.v, acc11, 0, 0, 0);
            acc20 = __builtin_amdgcn_mfma_f32_32x32x16_bf16(ae2.v, be.v, acc20, 0, 0, 0);
            acc21 = __builtin_amdgcn_mfma_f32_32x32x16_bf16(ae2.v, be.v, acc21, 0, 0, 0);
            acc30 = __builtin_amdgcn_mfma_f32_32x32x16_bf16(ae3.v, be.v, acc30, 0, 0, 0);
            acc31 = __builtin_amdgcn_mfma_f32_32x32x16_bf16(ae3.v, be.v, acc31, 0, 0, 0);
        }
        __syncthreads();                  // all waves done reading A/ext(mi)
        if (mi < 3) STAGE_AE(mi + 1)      // issue next stage (drains at barrier)

        // register-only fold: -2*acc already includes wq & mask
        #define FOLD(accv, rmv)                                                \
            { _Pragma("unroll") for (int r = 0; r < 16; ++r)                   \
                  rmv = fminf(rmv, -2.f * accv[r]); }
        FOLD(acc00, rm0) FOLD(acc10, rm0) FOLD(acc20, rm0) FOLD(acc30, rm0)
        FOLD(acc01, rm1) FOLD(acc11, rm1) FOLD(acc21, rm1) FOLD(acc31, rm1)
        #undef FOLD
        __syncthreads();                  // stage(mi+1) landed
    }

    // block-end epilogue: + shsq (commutes with min), scale, reduce, atomic
    const int colg = c0 + l31;
    rm0 = (rm0 + shsq[colg])      * (1.f / 512.f);
    rm1 = (rm1 + shsq[colg + 32]) * (1.f / 512.f);
    rm0 = fminf(rm0, __shfl_xor(rm0, 32, 64));
    rm1 = fminf(rm1, __shfl_xor(rm1, 32, 64));
    if (hi == 0) {
        atomicMin(&hmin[b * L_ + colg],      fenc(rm0));
        atomicMin(&hmin[b * L_ + colg + 32], fenc(rm1));
    }
}

// ---- final: gating + FC [B,L] -> [B,2] ----
__global__ __launch_bounds__(256) void k_final(const unsigned* __restrict__ hmin,
                                               const float* __restrict__ gating,
                                               const float* __restrict__ w,
                                               const float* __restrict__ bias,
                                               float* __restrict__ out) {
    const int b = blockIdx.x, t = threadIdx.x;       // 256 threads = L
    float v = fdec(hmin[b * L_ + t]);
    float g = 1.f / (1.f + __expf(-gating[t]));
    float mg = v * g;
    float p0 = mg * w[t];
    float p1 = mg * w[L_ + t];
    #pragma unroll
    for (int off = 32; off >= 1; off >>= 1) {
        p0 += __shfl_down(p0, off, 64);
        p1 += __shfl_down(p1, off, 64);
    }
    __shared__ float r0[4], r1[4];
    int wvi = t >> 6, ln = t & 63;
    if (ln == 0) { r0[wvi] = p0; r1[wvi] = p1; }
    __syncthreads();
    if (t == 0) {
        out[b * 2 + 0] = r0[0] + r0[1] + r0[2] + r0[3] + bias[0];
        out[b * 2 + 1] = r1[0] + r1[1] + r1[2] + r1[3] + bias[1];
    }
}

extern "C" void kernel_launch(void* const* d_in, const int* in_sizes, int n_in,
                              void* d_out, int out_size, void* d_ws, size_t ws_size,
                              hipStream_t stream) {
    const float* ts     = (const float*)d_in[0];
    const float* sh     = (const float*)d_in[1];
    const float* gating = (const float*)d_in[2];
    const float* fw     = (const float*)d_in[3];
    const float* fb     = (const float*)d_in[4];
    float* out = (float*)d_out;

    char* ws = (char*)d_ws;
    uint4*    tsb  = (uint4*)ws;                         // 4 MiB + 8 KB pad
    uint4*    shb  = (uint4*)(ws + 4202496);             // 256 KiB (col blobs)
    float*    shsq = (float*)(ws + 4464640);             // 1 KiB
    unsigned* hmin = (unsigned*)(ws + 4465664);          // 128 KiB
    unsigned* extg = (unsigned*)(ws + 4596736);          // 1 MiB

    k_prep<<<322, 256, 0, stream>>>(ts, sh, tsb, shb, shsq, extg, hmin);
    dim3 grid(NNT_, B_);
    k_main<<<grid, 256, 0, stream>>>(tsb, (const char*)shb, extg, shsq, hmin);
    k_final<<<128, 256, 0, stream>>>(hmin, gating, fw, fb, out);
}